// Round 2
// baseline (2463.122 us; speedup 1.0000x reference)
//
#include <hip/hip_runtime.h>
#include <hip/hip_bf16.h>
#include <stdint.h>

#define T_ 64
#define N_ 1024
#define L_ 128
#define H_ 512
#define C_ 64
#define S_ 771          // 1 + 1 + H + (L+1) + L
#define TN_ (T_*N_)

typedef unsigned short u16;
typedef unsigned int u32;
typedef float f32x4 __attribute__((ext_vector_type(4)));
typedef __bf16 bf16x8 __attribute__((ext_vector_type(8)));

__device__ __forceinline__ u16 f2bf(float f) {
  u32 u = __float_as_uint(f);
  u32 r = (u + 0x7FFFu + ((u >> 16) & 1u)) >> 16;
  return (u16)r;
}
__device__ __forceinline__ float bf2f(u16 u) {
  return __uint_as_float(((u32)u) << 16);
}
__device__ __forceinline__ void gload16(const void* g, void* l) {
  __builtin_amdgcn_global_load_lds((const __attribute__((address_space(1))) u32*)g,
                                   (__attribute__((address_space(3))) u32*)l, 16, 0, 0);
}
__device__ __forceinline__ float sigm(float x) { return 1.0f / (1.0f + __expf(-x)); }

// ---------------- prep kernels ----------------
__global__ void cast_f32_bf16(const float* __restrict__ src, u16* __restrict__ dst, int n) {
  int i = blockIdx.x * 256 + threadIdx.x;
  if (i < n) dst[i] = f2bf(src[i]);
}

__global__ void qscan(const float* __restrict__ hxs, const int* __restrict__ actions,
                      int* __restrict__ qpre, int* __restrict__ qpost) {
  int n = blockIdx.x * 256 + threadIdx.x;
  if (n >= N_) return;
  bool nz = false;
  for (int s = 0; s < S_; ++s) nz |= (hxs[(size_t)n * S_ + s] != 0.0f);
  int q = 0;
  if (nz) {  // fallback: argmax of stored one-hot p0
    float best = -3.4e38f;
    for (int l = 0; l < L_; ++l) {
      float v = hxs[(size_t)n * S_ + 2 + H_ + (L_ + 1) + l];
      if (v > best) { best = v; q = l; }
    }
  }
  for (int t = 0; t < T_; ++t) {
    qpre[t * N_ + n] = q;
    int a = actions[t * N_ + n];
    if (a < L_) q = a;
    qpost[t * N_ + n] = q;
  }
}

__global__ void hbf_init(const float* __restrict__ hxs, u16* __restrict__ hbf) {
  int i = blockIdx.x * 256 + threadIdx.x;
  if (i >= N_ * H_) return;
  int n = i >> 9, j = i & 511;
  hbf[i] = f2bf(hxs[(size_t)n * S_ + 2 + j]);
}

// A = [cond_t | emb[lines[n, qpre]]] as bf16 (TN x 576); one wave per row
__global__ void build_abuf(const float* __restrict__ cond, const float* __restrict__ emb,
                           const int* __restrict__ lines, const int* __restrict__ qpre,
                           u16* __restrict__ abuf) {
  int row = blockIdx.x * 4 + (threadIdx.x >> 6);
  int lane = threadIdx.x & 63;
  int n = row & (N_ - 1);
  int q = qpre[row];
  int line = lines[n * L_ + q];
  abuf[(size_t)row * 576 + lane] = f2bf(cond[(size_t)row * 64 + lane]);
  const float* er = emb + (size_t)line * H_;
  u16* ar = abuf + (size_t)row * 576 + 64;
  for (int j = lane; j < H_; j += 64) ar[j] = f2bf(er[j]);
}

// ---------------- phase-A GEMM (m97-style 128x128, BK=64, NT, bias[+relu], bf16 out) ----------------
#define BM 128
#define BN 128
#define BK 64
__global__ __launch_bounds__(256) void gemm_nt(
    const u16* __restrict__ A, int lda,
    const u16* __restrict__ B, int ldb,
    const float* __restrict__ bias,
    u16* __restrict__ C, int ldc,
    int K, int relu)
{
  __shared__ __align__(16) u16 lA[BM * BK];
  __shared__ __align__(16) u16 lB[BN * BK];
  int tid = threadIdx.x;
  int lane = tid & 63;
  int wave = tid >> 6;
  int wm = wave >> 1, wn = wave & 1;
  int m0 = blockIdx.y * BM;
  int n0 = blockIdx.x * BN;

  f32x4 acc[4][4];
  f32x4 zero = {0.f, 0.f, 0.f, 0.f};
#pragma unroll
  for (int i = 0; i < 4; ++i)
#pragma unroll
    for (int j = 0; j < 4; ++j) acc[i][j] = zero;

  int nkt = K / BK;
  for (int kt = 0; kt < nkt; ++kt) {
#pragma unroll
    for (int it = 0; it < 4; ++it) {
      int s = it * 256 + tid;
      int row = s >> 3, cs = s & 7;
      gload16(A + (size_t)(m0 + row) * lda + kt * BK + cs * 8,
              lA + (size_t)(it * 256 + (tid & ~63)) * 8);
      gload16(B + (size_t)(n0 + row) * ldb + kt * BK + cs * 8,
              lB + (size_t)(it * 256 + (tid & ~63)) * 8);
    }
    __syncthreads();
#pragma unroll
    for (int ks = 0; ks < 2; ++ks) {
      bf16x8 af[4], bfr[4];
#pragma unroll
      for (int fm = 0; fm < 4; ++fm) {
        int rowa = wm * 64 + fm * 16 + (lane & 15);
        af[fm] = *(const bf16x8*)&lA[rowa * BK + ks * 32 + ((lane >> 4) << 3)];
      }
#pragma unroll
      for (int fn = 0; fn < 4; ++fn) {
        int rowb = wn * 64 + fn * 16 + (lane & 15);
        bfr[fn] = *(const bf16x8*)&lB[rowb * BK + ks * 32 + ((lane >> 4) << 3)];
      }
#pragma unroll
      for (int fm = 0; fm < 4; ++fm)
#pragma unroll
        for (int fn = 0; fn < 4; ++fn)
          acc[fm][fn] = __builtin_amdgcn_mfma_f32_16x16x32_bf16(af[fm], bfr[fn], acc[fm][fn], 0, 0, 0);
    }
    __syncthreads();
  }
#pragma unroll
  for (int fm = 0; fm < 4; ++fm) {
#pragma unroll
    for (int fn = 0; fn < 4; ++fn) {
      int col = n0 + wn * 64 + fn * 16 + (lane & 15);
      float b = bias[col];
#pragma unroll
      for (int v = 0; v < 4; ++v) {
        int row = m0 + wm * 64 + fm * 16 + ((lane >> 4) << 2) + v;
        float val = acc[fm][fn][v] + b;
        if (relu) val = fmaxf(val, 0.0f);
        C[(size_t)row * ldc + col] = f2bf(val);
      }
    }
  }
}

// ---------------- phase-B: persistent GRU recurrence ----------------
// 256 WGs = 16 mt (n-blocks of 64) x 16 jt (j-blocks of 32). 1 WG/CU (96KB LDS).
// W_hh j-slice lives in LDS (swizzled) for all 64 steps; h carried in f32 regs.
// Cross-WG: per-mt 16-WG barrier on device-scope atomics, one slot per (t,mt).
__global__ __launch_bounds__(256) void gru_persistent(
    const u16* __restrict__ GI,    // (TN,1536) bf16, gi = x@W_ih^T + b_ih
    const u16* __restrict__ WHH,   // (3*512,512) bf16 row-major (= cast of W_hh)
    u16* __restrict__ Hbf0,        // ping: h_{t} bf16 (N,512), t even reads Hbf0
    u16* __restrict__ Hbf1,        // pong
    const float* __restrict__ hxs, // initial h f32 at [n*S_+2+j]
    const float* __restrict__ bhh, // (1536)
    float* __restrict__ out,
    int* __restrict__ bar)         // [T_][16] zeroed before launch
{
  __shared__ __align__(16) u16 lB[3 * 32 * 512];  // 96KB, swizzled
  int tid = threadIdx.x;
  int lane = tid & 63;
  int wave = tid >> 6;
  int bid = blockIdx.x;
  int mt = bid & 15, jt = bid >> 4;
  int n0 = mt * 64, j0 = jt * 32;

  // ---- load W_hh slice into LDS, swizzled: byte ^= (row&7)<<4 ----
  for (int i = tid; i < 6144; i += 256) {      // 6144 x 16B chunks
    int g = i >> 11;                            // gate
    int r = (i >> 6) & 31;                      // row within 32
    int c = i & 63;                             // 16B chunk within 1024B row
    const u16* src = WHH + ((size_t)(g * 512 + j0 + r)) * 512 + c * 8;
    int4 v = *(const int4*)src;
    int byte = (g << 15) + (r << 10) + (c << 4);
    byte ^= (r & 7) << 4;
    *(int4*)((char*)lB + byte) = v;
  }

  // ---- per-lane constants: biases, initial h ----
  float hreg[2][4];
  float brh[2], bzh[2], bnh[2];
#pragma unroll
  for (int fn = 0; fn < 2; ++fn) {
    int j = j0 + fn * 16 + (lane & 15);
    brh[fn] = bhh[j];
    bzh[fn] = bhh[512 + j];
    bnh[fn] = bhh[1024 + j];
#pragma unroll
    for (int v = 0; v < 4; ++v) {
      int n = n0 + wave * 16 + ((lane >> 4) << 2) + v;
      hreg[fn][v] = hxs[(size_t)n * S_ + 2 + j];
    }
  }
  __syncthreads();

  for (int t = 0; t < T_; ++t) {
    const u16* Hin = (t & 1) ? Hbf1 : Hbf0;
    u16* Hout = (t & 1) ? Hbf0 : Hbf1;
    if (t > 0) {
      const int* cptr = bar + (t - 1) * 16 + mt;
      while (__hip_atomic_load(cptr, __ATOMIC_RELAXED, __HIP_MEMORY_SCOPE_AGENT) < 16) {}
      __threadfence();   // acquire: invalidate L1/L2 so Hin reads are fresh
    }

    // ---- prefetch gi (24 bf16 scalars) ----
    const size_t tb = (size_t)t * N_;
    u16 gi[2][3][4];
#pragma unroll
    for (int fn = 0; fn < 2; ++fn) {
      int j = j0 + fn * 16 + (lane & 15);
#pragma unroll
      for (int v = 0; v < 4; ++v) {
        int nl = wave * 16 + ((lane >> 4) << 2) + v;
        const u16* gr = GI + (tb + n0 + nl) * 1536 + j;
#pragma unroll
        for (int g = 0; g < 3; ++g) gi[fn][g][v] = gr[g * 512];
      }
    }

    // ---- K-loop: gh = h_{t-1} @ W_hh^T for this (n,j) tile ----
    f32x4 zero = {0.f, 0.f, 0.f, 0.f};
    f32x4 acc[2][3] = {{zero, zero, zero}, {zero, zero, zero}};
    const u16* Arow = Hin + ((size_t)(n0 + wave * 16 + (lane & 15))) * 512 + ((lane >> 4) << 3);
#pragma unroll
    for (int kk = 0; kk < 16; ++kk) {
      bf16x8 a = *(const bf16x8*)(Arow + kk * 32);
#pragma unroll
      for (int fn = 0; fn < 2; ++fn) {
        int byte = ((fn * 16 + (lane & 15)) << 10) + kk * 64 + ((lane >> 4) << 4);
        byte ^= (lane & 7) << 4;
#pragma unroll
        for (int g = 0; g < 3; ++g) {
          bf16x8 b = *(const bf16x8*)((const char*)lB + (g << 15) + byte);
          acc[fn][g] = __builtin_amdgcn_mfma_f32_16x16x32_bf16(a, b, acc[fn][g], 0, 0, 0);
        }
      }
    }

    // ---- epilogue: gates, h update, writes ----
#pragma unroll
    for (int fn = 0; fn < 2; ++fn) {
      int j = j0 + fn * 16 + (lane & 15);
#pragma unroll
      for (int v = 0; v < 4; ++v) {
        int n = n0 + wave * 16 + ((lane >> 4) << 2) + v;
        float r = sigm(bf2f(gi[fn][0][v]) + acc[fn][0][v] + brh[fn]);
        float z = sigm(bf2f(gi[fn][1][v]) + acc[fn][1][v] + bzh[fn]);
        float nn = tanhf(bf2f(gi[fn][2][v]) + r * (acc[fn][2][v] + bnh[fn]));
        float h = (1.0f - z) * nn + z * hreg[fn][v];
        hreg[fn][v] = h;
        out[(tb + n) * S_ + 2 + j] = h;
        Hout[(size_t)n * 512 + j] = f2bf(h);
      }
    }

    __syncthreads();  // drains vmcnt: all threads' Hout stores complete
    if (tid == 0)
      __hip_atomic_fetch_add(bar + t * 16 + mt, 1, __ATOMIC_RELEASE, __HIP_MEMORY_SCOPE_AGENT);
  }
}

// ---------------- phase-C: heads + probs + p, batched over all (t,n) ----------------
__global__ __launch_bounds__(256) void heads_kernel(
    const float* __restrict__ Wc, const float* __restrict__ bc,
    const float* __restrict__ Wa, const float* __restrict__ ba,
    const int* __restrict__ actions, const int* __restrict__ qpre,
    const int* __restrict__ qpost, float* __restrict__ out)
{
  int row = blockIdx.x * 4 + (threadIdx.x >> 6);
  int lane = threadIdx.x & 63;
  const float* h = out + (size_t)row * S_ + 2;
  float pc = 0, p0 = 0, p1 = 0, p2 = 0, p3 = 0;
#pragma unroll
  for (int jj = 0; jj < 8; ++jj) {
    int k = lane * 8 + jj;
    float hv = h[k];
    pc += hv * Wc[k];
    p0 += hv * Wa[k];
    p1 += hv * Wa[512 + k];
    p2 += hv * Wa[1024 + k];
    p3 += hv * Wa[1536 + k];
  }
#pragma unroll
  for (int m = 1; m < 64; m <<= 1) {
    pc += __shfl_xor(pc, m);
    p0 += __shfl_xor(p0, m);
    p1 += __shfl_xor(p1, m);
    p2 += __shfl_xor(p2, m);
    p3 += __shfl_xor(p3, m);
  }
  float v = pc + bc[0];
  float k0 = p0 + ba[0], k1 = p1 + ba[1], k2 = p2 + ba[2], k3 = p3 + ba[3];
  float mx = fmaxf(k0, fmaxf(k1, k2));
  float e0 = __expf(k0 - mx), e1 = __expf(k1 - mx), e2 = __expf(k2 - mx);
  float es = e0 + e1 + e2;
  float l0 = e0 / es, l1 = e1 / es, l2 = e2 / es;
  float no = sigm(k3);
  float total = (1.0f - no) * (l0 + l1 + l2) + no;
  float sc = (1.0f - no) / total;
  int q = qpre[row], qp = qpost[row];
  int a = actions[row];
  if (lane == 0) {
    out[(size_t)row * S_] = (float)a;
    out[(size_t)row * S_ + 1] = v;
  }
  float* pr = out + (size_t)row * S_ + 2 + H_;
  for (int c = lane; c < L_ + 1; c += 64) {
    float val;
    if (c == L_) val = no / total;
    else {
      val = 0.f;
      if (q == 0)            { if (c == 0) val = l1 + l2; else if (c == 1) val = l0; }
      else if (q == L_ - 1)  { if (c == L_ - 2) val = l2; else if (c == L_ - 1) val = l0 + l1; }
      else                   { if (c == q - 1) val = l2; else if (c == q) val = l1; else if (c == q + 1) val = l0; }
      val *= sc;
    }
    pr[c] = val;
  }
  float* pp = pr + (L_ + 1);
  for (int c = lane; c < L_; c += 64) pp[c] = (c == qp) ? 1.0f : 0.0f;
}

__global__ void copy_last(float* __restrict__ out) {
  int i = blockIdx.x * 256 + threadIdx.x;
  if (i < N_ * S_) out[(size_t)TN_ * S_ + i] = out[(size_t)(T_ - 1) * N_ * S_ + i];
}

// ---------------- launch ----------------
extern "C" void kernel_launch(void* const* d_in, const int* in_sizes, int n_in,
                              void* d_out, int out_size, void* d_ws, size_t ws_size,
                              hipStream_t stream) {
  const float* cond = (const float*)d_in[0];
  const float* hxs  = (const float*)d_in[1];
  const float* emb  = (const float*)d_in[2];
  const float* W0   = (const float*)d_in[3];
  const float* b0   = (const float*)d_in[4];
  const float* W1   = (const float*)d_in[5];
  const float* b1   = (const float*)d_in[6];
  const float* W2   = (const float*)d_in[7];
  const float* b2   = (const float*)d_in[8];
  const float* Wih  = (const float*)d_in[9];
  const float* bih  = (const float*)d_in[10];
  const float* Whh  = (const float*)d_in[11];
  const float* bhh  = (const float*)d_in[12];
  const float* Wc   = (const float*)d_in[13];
  const float* bc   = (const float*)d_in[14];
  const float* Wa   = (const float*)d_in[15];
  const float* ba   = (const float*)d_in[16];
  const int* lines   = (const int*)d_in[17];
  const int* actions = (const int*)d_in[18];
  float* out = (float*)d_out;

  char* ws = (char*)d_ws;
  size_t off = 0;
  auto alloc = [&](size_t bytes) {
    char* p = ws + off;
    off += (bytes + 255) & ~(size_t)255;
    return p;
  };
  u16* P = (u16*)alloc((size_t)TN_ * 576 * 2);   // Abuf, then X2
  u16* Q = (u16*)alloc((size_t)TN_ * 512 * 2);   // X1, then X3
  u16* GIb = (u16*)alloc((size_t)TN_ * 1536 * 2); // gi (201MB)
  u16* Abuf = P;
  u16* X1 = Q;
  u16* X2 = P;
  u16* X3 = Q;
  u16* W0b = (u16*)alloc((size_t)512 * 576 * 2);
  u16* W1b = (u16*)alloc((size_t)512 * 512 * 2);
  u16* W2b = (u16*)alloc((size_t)512 * 512 * 2);
  u16* WIHb = (u16*)alloc((size_t)1536 * 512 * 2);
  u16* WHHb = (u16*)alloc((size_t)1536 * 512 * 2);
  int* qpre  = (int*)alloc((size_t)TN_ * 4);
  int* qpost = (int*)alloc((size_t)TN_ * 4);
  u16* hb0 = (u16*)alloc((size_t)N_ * 512 * 2);
  u16* hb1 = (u16*)alloc((size_t)N_ * 512 * 2);
  int* bar = (int*)alloc((size_t)T_ * 16 * 4);

  hipMemsetAsync(bar, 0, (size_t)T_ * 16 * 4, stream);

  cast_f32_bf16<<<(512 * 576 + 255) / 256, 256, 0, stream>>>(W0, W0b, 512 * 576);
  cast_f32_bf16<<<(512 * 512 + 255) / 256, 256, 0, stream>>>(W1, W1b, 512 * 512);
  cast_f32_bf16<<<(512 * 512 + 255) / 256, 256, 0, stream>>>(W2, W2b, 512 * 512);
  cast_f32_bf16<<<(1536 * 512 + 255) / 256, 256, 0, stream>>>(Wih, WIHb, 1536 * 512);
  cast_f32_bf16<<<(1536 * 512 + 255) / 256, 256, 0, stream>>>(Whh, WHHb, 1536 * 512);
  qscan<<<4, 256, 0, stream>>>(hxs, actions, qpre, qpost);
  hbf_init<<<(N_ * 512 + 255) / 256, 256, 0, stream>>>(hxs, hb0);
  build_abuf<<<TN_ / 4, 256, 0, stream>>>(cond, emb, lines, qpre, Abuf);

  gemm_nt<<<dim3(4, 512), 256, 0, stream>>>(Abuf, 576, W0b, 576, b0, X1, 512, 576, 1);
  gemm_nt<<<dim3(4, 512), 256, 0, stream>>>(X1, 512, W1b, 512, b1, X2, 512, 512, 1);
  gemm_nt<<<dim3(4, 512), 256, 0, stream>>>(X2, 512, W2b, 512, b2, X3, 512, 512, 1);
  gemm_nt<<<dim3(12, 512), 256, 0, stream>>>(X3, 512, WIHb, 512, bih, GIb, 1536, 512, 0);

  gru_persistent<<<256, 256, 0, stream>>>(GIb, WHHb, hb0, hb1, hxs, bhh, out, bar);

  heads_kernel<<<TN_ / 4, 256, 0, stream>>>(Wc, bc, Wa, ba, actions, qpre, qpost, out);
  copy_last<<<(N_ * S_ + 255) / 256, 256, 0, stream>>>(out);
}

// Round 3
// 1959.450 us; speedup vs baseline: 1.2570x; 1.2570x over previous
//
#include <hip/hip_runtime.h>
#include <hip/hip_bf16.h>
#include <stdint.h>

#define T_ 64
#define N_ 1024
#define L_ 128
#define H_ 512
#define C_ 64
#define S_ 771          // 1 + 1 + H + (L+1) + L
#define TN_ (T_*N_)

typedef unsigned short u16;
typedef unsigned int u32;
typedef float f32x4 __attribute__((ext_vector_type(4)));
typedef __bf16 bf16x8 __attribute__((ext_vector_type(8)));

__device__ __forceinline__ u16 f2bf(float f) {
  u32 u = __float_as_uint(f);
  u32 r = (u + 0x7FFFu + ((u >> 16) & 1u)) >> 16;
  return (u16)r;
}
__device__ __forceinline__ float bf2f(u16 u) {
  return __uint_as_float(((u32)u) << 16);
}
__device__ __forceinline__ void gload16(const void* g, void* l) {
  __builtin_amdgcn_global_load_lds((const __attribute__((address_space(1))) u32*)g,
                                   (__attribute__((address_space(3))) u32*)l, 16, 0, 0);
}
__device__ __forceinline__ float sigm(float x) { return 1.0f / (1.0f + __expf(-x)); }

// ---------------- prep kernels ----------------
__global__ void cast_f32_bf16(const float* __restrict__ src, u16* __restrict__ dst, int n) {
  int i = blockIdx.x * 256 + threadIdx.x;
  if (i < n) dst[i] = f2bf(src[i]);
}

__global__ void qscan(const float* __restrict__ hxs, const int* __restrict__ actions,
                      int* __restrict__ qpre, int* __restrict__ qpost) {
  int n = blockIdx.x * 256 + threadIdx.x;
  if (n >= N_) return;
  bool nz = false;
  for (int s = 0; s < S_; ++s) nz |= (hxs[(size_t)n * S_ + s] != 0.0f);
  int q = 0;
  if (nz) {  // fallback: argmax of stored one-hot p0
    float best = -3.4e38f;
    for (int l = 0; l < L_; ++l) {
      float v = hxs[(size_t)n * S_ + 2 + H_ + (L_ + 1) + l];
      if (v > best) { best = v; q = l; }
    }
  }
  for (int t = 0; t < T_; ++t) {
    qpre[t * N_ + n] = q;
    int a = actions[t * N_ + n];
    if (a < L_) q = a;
    qpost[t * N_ + n] = q;
  }
}

__global__ void hbf_init(const float* __restrict__ hxs, u16* __restrict__ hbf) {
  int i = blockIdx.x * 256 + threadIdx.x;
  if (i >= N_ * H_) return;
  int n = i >> 9, j = i & 511;
  hbf[i] = f2bf(hxs[(size_t)n * S_ + 2 + j]);
}

// A = [cond_t | emb[lines[n, qpre]]] as bf16 (TN x 576); one wave per row
__global__ void build_abuf(const float* __restrict__ cond, const float* __restrict__ emb,
                           const int* __restrict__ lines, const int* __restrict__ qpre,
                           u16* __restrict__ abuf) {
  int row = blockIdx.x * 4 + (threadIdx.x >> 6);
  int lane = threadIdx.x & 63;
  int n = row & (N_ - 1);
  int q = qpre[row];
  int line = lines[n * L_ + q];
  abuf[(size_t)row * 576 + lane] = f2bf(cond[(size_t)row * 64 + lane]);
  const float* er = emb + (size_t)line * H_;
  u16* ar = abuf + (size_t)row * 576 + 64;
  for (int j = lane; j < H_; j += 64) ar[j] = f2bf(er[j]);
}

// ---------------- phase-A GEMM (m97-style 128x128, BK=64, NT, bias[+relu], bf16 out) ----------------
#define BM 128
#define BN 128
#define BK 64
__global__ __launch_bounds__(256) void gemm_nt(
    const u16* __restrict__ A, int lda,
    const u16* __restrict__ B, int ldb,
    const float* __restrict__ bias,
    u16* __restrict__ C, int ldc,
    int K, int relu)
{
  __shared__ __align__(16) u16 lA[BM * BK];
  __shared__ __align__(16) u16 lB[BN * BK];
  int tid = threadIdx.x;
  int lane = tid & 63;
  int wave = tid >> 6;
  int wm = wave >> 1, wn = wave & 1;
  int m0 = blockIdx.y * BM;
  int n0 = blockIdx.x * BN;

  f32x4 acc[4][4];
  f32x4 zero = {0.f, 0.f, 0.f, 0.f};
#pragma unroll
  for (int i = 0; i < 4; ++i)
#pragma unroll
    for (int j = 0; j < 4; ++j) acc[i][j] = zero;

  int nkt = K / BK;
  for (int kt = 0; kt < nkt; ++kt) {
#pragma unroll
    for (int it = 0; it < 4; ++it) {
      int s = it * 256 + tid;
      int row = s >> 3, cs = s & 7;
      gload16(A + (size_t)(m0 + row) * lda + kt * BK + cs * 8,
              lA + (size_t)(it * 256 + (tid & ~63)) * 8);
      gload16(B + (size_t)(n0 + row) * ldb + kt * BK + cs * 8,
              lB + (size_t)(it * 256 + (tid & ~63)) * 8);
    }
    __syncthreads();
#pragma unroll
    for (int ks = 0; ks < 2; ++ks) {
      bf16x8 af[4], bfr[4];
#pragma unroll
      for (int fm = 0; fm < 4; ++fm) {
        int rowa = wm * 64 + fm * 16 + (lane & 15);
        af[fm] = *(const bf16x8*)&lA[rowa * BK + ks * 32 + ((lane >> 4) << 3)];
      }
#pragma unroll
      for (int fn = 0; fn < 4; ++fn) {
        int rowb = wn * 64 + fn * 16 + (lane & 15);
        bfr[fn] = *(const bf16x8*)&lB[rowb * BK + ks * 32 + ((lane >> 4) << 3)];
      }
#pragma unroll
      for (int fm = 0; fm < 4; ++fm)
#pragma unroll
        for (int fn = 0; fn < 4; ++fn)
          acc[fm][fn] = __builtin_amdgcn_mfma_f32_16x16x32_bf16(af[fm], bfr[fn], acc[fm][fn], 0, 0, 0);
    }
    __syncthreads();
  }
#pragma unroll
  for (int fm = 0; fm < 4; ++fm) {
#pragma unroll
    for (int fn = 0; fn < 4; ++fn) {
      int col = n0 + wn * 64 + fn * 16 + (lane & 15);
      float b = bias[col];
#pragma unroll
      for (int v = 0; v < 4; ++v) {
        int row = m0 + wm * 64 + fm * 16 + ((lane >> 4) << 2) + v;
        float val = acc[fm][fn][v] + b;
        if (relu) val = fmaxf(val, 0.0f);
        C[(size_t)row * ldc + col] = f2bf(val);
      }
    }
  }
}

// ---------------- phase-B: persistent GRU recurrence ----------------
// 256 WGs = 16 mt (n-blocks of 64) x 16 jt (j-blocks of 32). 1 WG/CU (96KB LDS).
// W_hh j-slice lives in LDS (swizzled) for all 64 steps; h carried in f32 regs.
// Cross-WG: per-mt 16-WG barrier; SINGLE-THREAD spin with s_sleep backoff
// (all-thread spin + all-thread threadfence was the round-2 pathology).
__global__ __launch_bounds__(256) void gru_persistent(
    const u16* __restrict__ GI,    // (TN,1536) bf16, gi = x@W_ih^T + b_ih
    const u16* __restrict__ WHH,   // (3*512,512) bf16 row-major (= cast of W_hh)
    u16* __restrict__ Hbf0,        // ping: h_{t} bf16 (N,512), t even reads Hbf0
    u16* __restrict__ Hbf1,        // pong
    const float* __restrict__ hxs, // initial h f32 at [n*S_+2+j]
    const float* __restrict__ bhh, // (1536)
    float* __restrict__ out,
    int* __restrict__ bar)         // [T_][16] zeroed before launch
{
  __shared__ __align__(16) u16 lB[3 * 32 * 512];  // 96KB, swizzled
  int tid = threadIdx.x;
  int lane = tid & 63;
  int wave = tid >> 6;
  int bid = blockIdx.x;
  int mt = bid & 15, jt = bid >> 4;
  int n0 = mt * 64, j0 = jt * 32;

  // ---- load W_hh slice into LDS, swizzled: byte ^= (row&7)<<4 ----
  for (int i = tid; i < 6144; i += 256) {      // 6144 x 16B chunks
    int g = i >> 11;                            // gate
    int r = (i >> 6) & 31;                      // row within 32
    int c = i & 63;                             // 16B chunk within 1024B row
    const u16* src = WHH + ((size_t)(g * 512 + j0 + r)) * 512 + c * 8;
    int4 v = *(const int4*)src;
    int byte = (g << 15) + (r << 10) + (c << 4);
    byte ^= (r & 7) << 4;
    *(int4*)((char*)lB + byte) = v;
  }

  // ---- per-lane constants: biases, initial h ----
  float hreg[2][4];
  float brh[2], bzh[2], bnh[2];
#pragma unroll
  for (int fn = 0; fn < 2; ++fn) {
    int j = j0 + fn * 16 + (lane & 15);
    brh[fn] = bhh[j];
    bzh[fn] = bhh[512 + j];
    bnh[fn] = bhh[1024 + j];
#pragma unroll
    for (int v = 0; v < 4; ++v) {
      int n = n0 + wave * 16 + ((lane >> 4) << 2) + v;
      hreg[fn][v] = hxs[(size_t)n * S_ + 2 + j];
    }
  }
  __syncthreads();

  for (int t = 0; t < T_; ++t) {
    const u16* Hin = (t & 1) ? Hbf1 : Hbf0;
    u16* Hout = (t & 1) ? Hbf0 : Hbf1;

    // ---- prefetch gi (24 bf16 scalars) — independent of Hin, hides under spin ----
    const size_t tb = (size_t)t * N_;
    u16 gi[2][3][4];
#pragma unroll
    for (int fn = 0; fn < 2; ++fn) {
      int j = j0 + fn * 16 + (lane & 15);
#pragma unroll
      for (int v = 0; v < 4; ++v) {
        int nl = wave * 16 + ((lane >> 4) << 2) + v;
        const u16* gr = GI + (tb + n0 + nl) * 1536 + j;
#pragma unroll
        for (int g = 0; g < 3; ++g) gi[fn][g][v] = gr[g * 512];
      }
    }

    if (t > 0) {
      if (tid == 0) {
        const int* cptr = bar + (t - 1) * 16 + mt;
        while (__hip_atomic_load(cptr, __ATOMIC_RELAXED, __HIP_MEMORY_SCOPE_AGENT) < 16)
          __builtin_amdgcn_s_sleep(2);
        __threadfence();   // acquire: one L1-inv covers the whole CU/WG
      }
      __syncthreads();
    }

    // ---- K-loop: gh = h_{t-1} @ W_hh^T for this (n,j) tile ----
    f32x4 zero = {0.f, 0.f, 0.f, 0.f};
    f32x4 acc[2][3] = {{zero, zero, zero}, {zero, zero, zero}};
    const u16* Arow = Hin + ((size_t)(n0 + wave * 16 + (lane & 15))) * 512 + ((lane >> 4) << 3);
#pragma unroll
    for (int kk = 0; kk < 16; ++kk) {
      bf16x8 a = *(const bf16x8*)(Arow + kk * 32);
#pragma unroll
      for (int fn = 0; fn < 2; ++fn) {
        int byte = ((fn * 16 + (lane & 15)) << 10) + kk * 64 + ((lane >> 4) << 4);
        byte ^= (lane & 7) << 4;
#pragma unroll
        for (int g = 0; g < 3; ++g) {
          bf16x8 b = *(const bf16x8*)((const char*)lB + (g << 15) + byte);
          acc[fn][g] = __builtin_amdgcn_mfma_f32_16x16x32_bf16(a, b, acc[fn][g], 0, 0, 0);
        }
      }
    }

    // ---- epilogue: gates, h update, writes ----
#pragma unroll
    for (int fn = 0; fn < 2; ++fn) {
      int j = j0 + fn * 16 + (lane & 15);
#pragma unroll
      for (int v = 0; v < 4; ++v) {
        int n = n0 + wave * 16 + ((lane >> 4) << 2) + v;
        float r = sigm(bf2f(gi[fn][0][v]) + acc[fn][0][v] + brh[fn]);
        float z = sigm(bf2f(gi[fn][1][v]) + acc[fn][1][v] + bzh[fn]);
        float nn = tanhf(bf2f(gi[fn][2][v]) + r * (acc[fn][2][v] + bnh[fn]));
        float h = (1.0f - z) * nn + z * hreg[fn][v];
        hreg[fn][v] = h;
        out[(tb + n) * S_ + 2 + j] = h;
        Hout[(size_t)n * 512 + j] = f2bf(h);
      }
    }

    if (t < T_ - 1) {
      __syncthreads();  // compiler emits vmcnt(0) drain: Hout stores complete
      if (tid == 0)
        __hip_atomic_fetch_add(bar + t * 16 + mt, 1, __ATOMIC_RELEASE, __HIP_MEMORY_SCOPE_AGENT);
    }
  }
}

// ---------------- phase-C: heads + probs + p, batched over all (t,n) ----------------
__global__ __launch_bounds__(256) void heads_kernel(
    const float* __restrict__ Wc, const float* __restrict__ bc,
    const float* __restrict__ Wa, const float* __restrict__ ba,
    const int* __restrict__ actions, const int* __restrict__ qpre,
    const int* __restrict__ qpost, float* __restrict__ out)
{
  int row = blockIdx.x * 4 + (threadIdx.x >> 6);
  int lane = threadIdx.x & 63;
  const float* h = out + (size_t)row * S_ + 2;
  float pc = 0, p0 = 0, p1 = 0, p2 = 0, p3 = 0;
#pragma unroll
  for (int jj = 0; jj < 8; ++jj) {
    int k = lane * 8 + jj;
    float hv = h[k];
    pc += hv * Wc[k];
    p0 += hv * Wa[k];
    p1 += hv * Wa[512 + k];
    p2 += hv * Wa[1024 + k];
    p3 += hv * Wa[1536 + k];
  }
#pragma unroll
  for (int m = 1; m < 64; m <<= 1) {
    pc += __shfl_xor(pc, m);
    p0 += __shfl_xor(p0, m);
    p1 += __shfl_xor(p1, m);
    p2 += __shfl_xor(p2, m);
    p3 += __shfl_xor(p3, m);
  }
  float v = pc + bc[0];
  float k0 = p0 + ba[0], k1 = p1 + ba[1], k2 = p2 + ba[2], k3 = p3 + ba[3];
  float mx = fmaxf(k0, fmaxf(k1, k2));
  float e0 = __expf(k0 - mx), e1 = __expf(k1 - mx), e2 = __expf(k2 - mx);
  float es = e0 + e1 + e2;
  float l0 = e0 / es, l1 = e1 / es, l2 = e2 / es;
  float no = sigm(k3);
  float total = (1.0f - no) * (l0 + l1 + l2) + no;
  float sc = (1.0f - no) / total;
  int q = qpre[row], qp = qpost[row];
  int a = actions[row];
  if (lane == 0) {
    out[(size_t)row * S_] = (float)a;
    out[(size_t)row * S_ + 1] = v;
  }
  float* pr = out + (size_t)row * S_ + 2 + H_;
  for (int c = lane; c < L_ + 1; c += 64) {
    float val;
    if (c == L_) val = no / total;
    else {
      val = 0.f;
      if (q == 0)            { if (c == 0) val = l1 + l2; else if (c == 1) val = l0; }
      else if (q == L_ - 1)  { if (c == L_ - 2) val = l2; else if (c == L_ - 1) val = l0 + l1; }
      else                   { if (c == q - 1) val = l2; else if (c == q) val = l1; else if (c == q + 1) val = l0; }
      val *= sc;
    }
    pr[c] = val;
  }
  float* pp = pr + (L_ + 1);
  for (int c = lane; c < L_; c += 64) pp[c] = (c == qp) ? 1.0f : 0.0f;
}

__global__ void copy_last(float* __restrict__ out) {
  int i = blockIdx.x * 256 + threadIdx.x;
  if (i < N_ * S_) out[(size_t)TN_ * S_ + i] = out[(size_t)(T_ - 1) * N_ * S_ + i];
}

// ---------------- launch ----------------
extern "C" void kernel_launch(void* const* d_in, const int* in_sizes, int n_in,
                              void* d_out, int out_size, void* d_ws, size_t ws_size,
                              hipStream_t stream) {
  const float* cond = (const float*)d_in[0];
  const float* hxs  = (const float*)d_in[1];
  const float* emb  = (const float*)d_in[2];
  const float* W0   = (const float*)d_in[3];
  const float* b0   = (const float*)d_in[4];
  const float* W1   = (const float*)d_in[5];
  const float* b1   = (const float*)d_in[6];
  const float* W2   = (const float*)d_in[7];
  const float* b2   = (const float*)d_in[8];
  const float* Wih  = (const float*)d_in[9];
  const float* bih  = (const float*)d_in[10];
  const float* Whh  = (const float*)d_in[11];
  const float* bhh  = (const float*)d_in[12];
  const float* Wc   = (const float*)d_in[13];
  const float* bc   = (const float*)d_in[14];
  const float* Wa   = (const float*)d_in[15];
  const float* ba   = (const float*)d_in[16];
  const int* lines   = (const int*)d_in[17];
  const int* actions = (const int*)d_in[18];
  float* out = (float*)d_out;

  char* ws = (char*)d_ws;
  size_t off = 0;
  auto alloc = [&](size_t bytes) {
    char* p = ws + off;
    off += (bytes + 255) & ~(size_t)255;
    return p;
  };
  u16* P = (u16*)alloc((size_t)TN_ * 576 * 2);   // Abuf, then X2
  u16* Q = (u16*)alloc((size_t)TN_ * 512 * 2);   // X1, then X3
  u16* GIb = (u16*)alloc((size_t)TN_ * 1536 * 2); // gi (201MB)
  u16* Abuf = P;
  u16* X1 = Q;
  u16* X2 = P;
  u16* X3 = Q;
  u16* W0b = (u16*)alloc((size_t)512 * 576 * 2);
  u16* W1b = (u16*)alloc((size_t)512 * 512 * 2);
  u16* W2b = (u16*)alloc((size_t)512 * 512 * 2);
  u16* WIHb = (u16*)alloc((size_t)1536 * 512 * 2);
  u16* WHHb = (u16*)alloc((size_t)1536 * 512 * 2);
  int* qpre  = (int*)alloc((size_t)TN_ * 4);
  int* qpost = (int*)alloc((size_t)TN_ * 4);
  u16* hb0 = (u16*)alloc((size_t)N_ * 512 * 2);
  u16* hb1 = (u16*)alloc((size_t)N_ * 512 * 2);
  int* bar = (int*)alloc((size_t)T_ * 16 * 4);

  hipMemsetAsync(bar, 0, (size_t)T_ * 16 * 4, stream);

  cast_f32_bf16<<<(512 * 576 + 255) / 256, 256, 0, stream>>>(W0, W0b, 512 * 576);
  cast_f32_bf16<<<(512 * 512 + 255) / 256, 256, 0, stream>>>(W1, W1b, 512 * 512);
  cast_f32_bf16<<<(512 * 512 + 255) / 256, 256, 0, stream>>>(W2, W2b, 512 * 512);
  cast_f32_bf16<<<(1536 * 512 + 255) / 256, 256, 0, stream>>>(Wih, WIHb, 1536 * 512);
  cast_f32_bf16<<<(1536 * 512 + 255) / 256, 256, 0, stream>>>(Whh, WHHb, 1536 * 512);
  qscan<<<4, 256, 0, stream>>>(hxs, actions, qpre, qpost);
  hbf_init<<<(N_ * 512 + 255) / 256, 256, 0, stream>>>(hxs, hb0);
  build_abuf<<<TN_ / 4, 256, 0, stream>>>(cond, emb, lines, qpre, Abuf);

  gemm_nt<<<dim3(4, 512), 256, 0, stream>>>(Abuf, 576, W0b, 576, b0, X1, 512, 576, 1);
  gemm_nt<<<dim3(4, 512), 256, 0, stream>>>(X1, 512, W1b, 512, b1, X2, 512, 512, 1);
  gemm_nt<<<dim3(4, 512), 256, 0, stream>>>(X2, 512, W2b, 512, b2, X3, 512, 512, 1);
  gemm_nt<<<dim3(12, 512), 256, 0, stream>>>(X3, 512, WIHb, 512, bih, GIb, 1536, 512, 0);

  gru_persistent<<<256, 256, 0, stream>>>(GIb, WHHb, hb0, hb1, hxs, bhh, out, bar);

  heads_kernel<<<TN_ / 4, 256, 0, stream>>>(Wc, bc, Wa, ba, actions, qpre, qpost, out);
  copy_last<<<(N_ * S_ + 255) / 256, 256, 0, stream>>>(out);
}

// Round 4
// 899.386 us; speedup vs baseline: 2.7387x; 2.1787x over previous
//
#include <hip/hip_runtime.h>
#include <hip/hip_bf16.h>
#include <stdint.h>

#define T_ 64
#define N_ 1024
#define L_ 128
#define H_ 512
#define C_ 64
#define S_ 771          // 1 + 1 + H + (L+1) + L
#define TN_ (T_*N_)

typedef unsigned short u16;
typedef unsigned int u32;
typedef float f32x4 __attribute__((ext_vector_type(4)));
typedef __bf16 bf16x8 __attribute__((ext_vector_type(8)));

__device__ __forceinline__ u16 f2bf(float f) {
  u32 u = __float_as_uint(f);
  u32 r = (u + 0x7FFFu + ((u >> 16) & 1u)) >> 16;
  return (u16)r;
}
__device__ __forceinline__ float bf2f(u16 u) {
  return __uint_as_float(((u32)u) << 16);
}
__device__ __forceinline__ void gload16(const void* g, void* l) {
  __builtin_amdgcn_global_load_lds((const __attribute__((address_space(1))) u32*)g,
                                   (__attribute__((address_space(3))) u32*)l, 16, 0, 0);
}
__device__ __forceinline__ float sigm(float x) { return 1.0f / (1.0f + __expf(-x)); }

// LLC-coherent (device-scope) accesses: sc0 sc1 = bypass/write-through L1+L2.
// These carry the h exchange between WGs with NO wbl2/inv cache maintenance.
__device__ __forceinline__ bf16x8 load_cc(const u16* p) {
  bf16x8 v;
  asm volatile("global_load_dwordx4 %0, %1, off sc0 sc1" : "=v"(v) : "v"(p) : "memory");
  return v;
}
__device__ __forceinline__ void store_cc_short(u16* p, u32 val) {
  asm volatile("global_store_short %0, %1, off sc0 sc1" :: "v"(p), "v"(val) : "memory");
}
__device__ __forceinline__ void wait_vm(int n) {
  if (n == 0) asm volatile("s_waitcnt vmcnt(0)" ::: "memory");
  else        asm volatile("s_waitcnt vmcnt(8)" ::: "memory");
  __builtin_amdgcn_sched_barrier(0);
}

// ---------------- prep kernels ----------------
__global__ void cast_f32_bf16(const float* __restrict__ src, u16* __restrict__ dst, int n) {
  int i = blockIdx.x * 256 + threadIdx.x;
  if (i < n) dst[i] = f2bf(src[i]);
}

__global__ void qscan(const float* __restrict__ hxs, const int* __restrict__ actions,
                      int* __restrict__ qpre, int* __restrict__ qpost) {
  int n = blockIdx.x * 256 + threadIdx.x;
  if (n >= N_) return;
  bool nz = false;
  for (int s = 0; s < S_; ++s) nz |= (hxs[(size_t)n * S_ + s] != 0.0f);
  int q = 0;
  if (nz) {  // fallback: argmax of stored one-hot p0
    float best = -3.4e38f;
    for (int l = 0; l < L_; ++l) {
      float v = hxs[(size_t)n * S_ + 2 + H_ + (L_ + 1) + l];
      if (v > best) { best = v; q = l; }
    }
  }
  for (int t = 0; t < T_; ++t) {
    qpre[t * N_ + n] = q;
    int a = actions[t * N_ + n];
    if (a < L_) q = a;
    qpost[t * N_ + n] = q;
  }
}

__global__ void hbf_init(const float* __restrict__ hxs, u16* __restrict__ hbf) {
  int i = blockIdx.x * 256 + threadIdx.x;
  if (i >= N_ * H_) return;
  int n = i >> 9, j = i & 511;
  hbf[i] = f2bf(hxs[(size_t)n * S_ + 2 + j]);
}

// A = [cond_t | emb[lines[n, qpre]]] as bf16 (TN x 576); one wave per row
__global__ void build_abuf(const float* __restrict__ cond, const float* __restrict__ emb,
                           const int* __restrict__ lines, const int* __restrict__ qpre,
                           u16* __restrict__ abuf) {
  int row = blockIdx.x * 4 + (threadIdx.x >> 6);
  int lane = threadIdx.x & 63;
  int n = row & (N_ - 1);
  int q = qpre[row];
  int line = lines[n * L_ + q];
  abuf[(size_t)row * 576 + lane] = f2bf(cond[(size_t)row * 64 + lane]);
  const float* er = emb + (size_t)line * H_;
  u16* ar = abuf + (size_t)row * 576 + 64;
  for (int j = lane; j < H_; j += 64) ar[j] = f2bf(er[j]);
}

// ---------------- phase-A GEMM (m97-style 128x128, BK=64, NT, bias[+relu], bf16 out) ----------------
#define BM 128
#define BN 128
#define BK 64
__global__ __launch_bounds__(256) void gemm_nt(
    const u16* __restrict__ A, int lda,
    const u16* __restrict__ B, int ldb,
    const float* __restrict__ bias,
    u16* __restrict__ C, int ldc,
    int K, int relu)
{
  __shared__ __align__(16) u16 lA[BM * BK];
  __shared__ __align__(16) u16 lB[BN * BK];
  int tid = threadIdx.x;
  int lane = tid & 63;
  int wave = tid >> 6;
  int wm = wave >> 1, wn = wave & 1;
  int m0 = blockIdx.y * BM;
  int n0 = blockIdx.x * BN;

  f32x4 acc[4][4];
  f32x4 zero = {0.f, 0.f, 0.f, 0.f};
#pragma unroll
  for (int i = 0; i < 4; ++i)
#pragma unroll
    for (int j = 0; j < 4; ++j) acc[i][j] = zero;

  int nkt = K / BK;
  for (int kt = 0; kt < nkt; ++kt) {
#pragma unroll
    for (int it = 0; it < 4; ++it) {
      int s = it * 256 + tid;
      int row = s >> 3, cs = s & 7;
      gload16(A + (size_t)(m0 + row) * lda + kt * BK + cs * 8,
              lA + (size_t)(it * 256 + (tid & ~63)) * 8);
      gload16(B + (size_t)(n0 + row) * ldb + kt * BK + cs * 8,
              lB + (size_t)(it * 256 + (tid & ~63)) * 8);
    }
    __syncthreads();
#pragma unroll
    for (int ks = 0; ks < 2; ++ks) {
      bf16x8 af[4], bfr[4];
#pragma unroll
      for (int fm = 0; fm < 4; ++fm) {
        int rowa = wm * 64 + fm * 16 + (lane & 15);
        af[fm] = *(const bf16x8*)&lA[rowa * BK + ks * 32 + ((lane >> 4) << 3)];
      }
#pragma unroll
      for (int fn = 0; fn < 4; ++fn) {
        int rowb = wn * 64 + fn * 16 + (lane & 15);
        bfr[fn] = *(const bf16x8*)&lB[rowb * BK + ks * 32 + ((lane >> 4) << 3)];
      }
#pragma unroll
      for (int fm = 0; fm < 4; ++fm)
#pragma unroll
        for (int fn = 0; fn < 4; ++fn)
          acc[fm][fn] = __builtin_amdgcn_mfma_f32_16x16x32_bf16(af[fm], bfr[fn], acc[fm][fn], 0, 0, 0);
    }
    __syncthreads();
  }
#pragma unroll
  for (int fm = 0; fm < 4; ++fm) {
#pragma unroll
    for (int fn = 0; fn < 4; ++fn) {
      int col = n0 + wn * 64 + fn * 16 + (lane & 15);
      float b = bias[col];
#pragma unroll
      for (int v = 0; v < 4; ++v) {
        int row = m0 + wm * 64 + fm * 16 + ((lane >> 4) << 2) + v;
        float val = acc[fm][fn][v] + b;
        if (relu) val = fmaxf(val, 0.0f);
        C[(size_t)row * ldc + col] = f2bf(val);
      }
    }
  }
}

// ---------------- phase-B: persistent GRU recurrence ----------------
// 256 WGs = 16 mt (n-blocks of 64) x 16 jt (j-blocks of 32). 1 WG/CU (96KB LDS).
// W_hh j-slice in LDS (swizzled) for all 64 steps; h carried in f32 regs.
// h exchange via LLC-coherent sc0sc1 loads/stores; barrier atomics RELAXED
// (round-3 pathology: release/acquire fences emitted full-L2 wbl2/inv per WG-step).
__global__ __launch_bounds__(256, 1) void gru_persistent(
    const u16* __restrict__ GI,    // (TN,1536) bf16, gi = x@W_ih^T + b_ih
    const u16* __restrict__ WHH,   // (3*512,512) bf16 row-major (= cast of W_hh)
    u16* __restrict__ Hbf0,        // ping: h_{t} bf16 (N,512), t even reads Hbf0
    u16* __restrict__ Hbf1,        // pong
    const float* __restrict__ hxs, // initial h f32 at [n*S_+2+j]
    const float* __restrict__ bhh, // (1536)
    float* __restrict__ out,
    int* __restrict__ bar)         // [16][T_] zeroed before launch (1 line/group)
{
  __shared__ __align__(16) u16 lB[3 * 32 * 512];  // 96KB, swizzled
  int tid = threadIdx.x;
  int lane = tid & 63;
  int wave = tid >> 6;
  int bid = blockIdx.x;
  int mt = bid & 15, jt = bid >> 4;
  int n0 = mt * 64, j0 = jt * 32;

  // ---- load W_hh slice into LDS, swizzled: byte ^= (row&7)<<4 ----
  for (int i = tid; i < 6144; i += 256) {      // 6144 x 16B chunks
    int g = i >> 11;                            // gate
    int r = (i >> 6) & 31;                      // row within 32
    int c = i & 63;                             // 16B chunk within 1024B row
    const u16* src = WHH + ((size_t)(g * 512 + j0 + r)) * 512 + c * 8;
    int4 v = *(const int4*)src;
    int byte = (g << 15) + (r << 10) + (c << 4);
    byte ^= (r & 7) << 4;
    *(int4*)((char*)lB + byte) = v;
  }

  // ---- per-lane constants: biases, initial h ----
  float hreg[2][4];
  float brh[2], bzh[2], bnh[2];
#pragma unroll
  for (int fn = 0; fn < 2; ++fn) {
    int j = j0 + fn * 16 + (lane & 15);
    brh[fn] = bhh[j];
    bzh[fn] = bhh[512 + j];
    bnh[fn] = bhh[1024 + j];
#pragma unroll
    for (int v = 0; v < 4; ++v) {
      int n = n0 + wave * 16 + ((lane >> 4) << 2) + v;
      hreg[fn][v] = hxs[(size_t)n * S_ + 2 + j];
    }
  }
  __syncthreads();

  for (int t = 0; t < T_; ++t) {
    const u16* Hin = (t & 1) ? Hbf1 : Hbf0;
    u16* Hout = (t & 1) ? Hbf0 : Hbf1;

    // ---- prefetch gi (24 bf16 scalars) — independent of Hin, hides under spin ----
    const size_t tb = (size_t)t * N_;
    u16 gi[2][3][4];
#pragma unroll
    for (int fn = 0; fn < 2; ++fn) {
      int j = j0 + fn * 16 + (lane & 15);
#pragma unroll
      for (int v = 0; v < 4; ++v) {
        int nl = wave * 16 + ((lane >> 4) << 2) + v;
        const u16* gr = GI + (tb + n0 + nl) * 1536 + j;
#pragma unroll
        for (int g = 0; g < 3; ++g) gi[fn][g][v] = gr[g * 512];
      }
    }

    if (t > 0) {
      if (tid == 0) {
        const int* cptr = bar + mt * T_ + (t - 1);
        while (__hip_atomic_load(cptr, __ATOMIC_RELAXED, __HIP_MEMORY_SCOPE_AGENT) < 16)
          __builtin_amdgcn_s_sleep(2);
      }
      __syncthreads();   // releases whole WG once flag seen; no cache maintenance
    }

    // ---- preload A-fragments (h_{t-1}) via LLC-coherent loads ----
    bf16x8 areg[16];
    const u16* Arow = Hin + ((size_t)(n0 + wave * 16 + (lane & 15))) * 512 + ((lane >> 4) << 3);
#pragma unroll
    for (int kk = 0; kk < 16; ++kk) areg[kk] = load_cc(Arow + kk * 32);

    // ---- K-loop: gh = h_{t-1} @ W_hh^T, split so compute overlaps load tail ----
    f32x4 zero = {0.f, 0.f, 0.f, 0.f};
    f32x4 acc[2][3] = {{zero, zero, zero}, {zero, zero, zero}};
    wait_vm(8);   // first 8 A-loads complete (vmcnt ordered)
#pragma unroll
    for (int kk = 0; kk < 8; ++kk) {
#pragma unroll
      for (int fn = 0; fn < 2; ++fn) {
        int byte = ((fn * 16 + (lane & 15)) << 10) + kk * 64 + ((lane >> 4) << 4);
        byte ^= (lane & 7) << 4;
#pragma unroll
        for (int g = 0; g < 3; ++g) {
          bf16x8 b = *(const bf16x8*)((const char*)lB + (g << 15) + byte);
          acc[fn][g] = __builtin_amdgcn_mfma_f32_16x16x32_bf16(areg[kk], b, acc[fn][g], 0, 0, 0);
        }
      }
    }
    wait_vm(0);   // remaining A-loads (and gi) complete
#pragma unroll
    for (int kk = 8; kk < 16; ++kk) {
#pragma unroll
      for (int fn = 0; fn < 2; ++fn) {
        int byte = ((fn * 16 + (lane & 15)) << 10) + kk * 64 + ((lane >> 4) << 4);
        byte ^= (lane & 7) << 4;
#pragma unroll
        for (int g = 0; g < 3; ++g) {
          bf16x8 b = *(const bf16x8*)((const char*)lB + (g << 15) + byte);
          acc[fn][g] = __builtin_amdgcn_mfma_f32_16x16x32_bf16(areg[kk], b, acc[fn][g], 0, 0, 0);
        }
      }
    }

    // ---- epilogue: gates, h update, writes ----
#pragma unroll
    for (int fn = 0; fn < 2; ++fn) {
      int j = j0 + fn * 16 + (lane & 15);
#pragma unroll
      for (int v = 0; v < 4; ++v) {
        int n = n0 + wave * 16 + ((lane >> 4) << 2) + v;
        float r = sigm(bf2f(gi[fn][0][v]) + acc[fn][0][v] + brh[fn]);
        float z = sigm(bf2f(gi[fn][1][v]) + acc[fn][1][v] + bzh[fn]);
        float nn = tanhf(bf2f(gi[fn][2][v]) + r * (acc[fn][2][v] + bnh[fn]));
        float h = (1.0f - z) * nn + z * hreg[fn][v];
        hreg[fn][v] = h;
        out[(tb + n) * S_ + 2 + j] = h;                       // plain (flushed at kernel end)
        store_cc_short(Hout + (size_t)n * 512 + j, (u32)f2bf(h));  // LLC write-through
      }
    }

    if (t < T_ - 1) {
      wait_vm(0);        // sc1 stores visible at LLC before flag
      __syncthreads();   // all threads' stores drained
      if (tid == 0)
        __hip_atomic_fetch_add(bar + mt * T_ + t, 1, __ATOMIC_RELAXED, __HIP_MEMORY_SCOPE_AGENT);
    }
  }
}

// ---------------- phase-C: heads + probs + p, batched over all (t,n) ----------------
__global__ __launch_bounds__(256) void heads_kernel(
    const float* __restrict__ Wc, const float* __restrict__ bc,
    const float* __restrict__ Wa, const float* __restrict__ ba,
    const int* __restrict__ actions, const int* __restrict__ qpre,
    const int* __restrict__ qpost, float* __restrict__ out)
{
  int row = blockIdx.x * 4 + (threadIdx.x >> 6);
  int lane = threadIdx.x & 63;
  const float* h = out + (size_t)row * S_ + 2;
  float pc = 0, p0 = 0, p1 = 0, p2 = 0, p3 = 0;
#pragma unroll
  for (int jj = 0; jj < 8; ++jj) {
    int k = lane * 8 + jj;
    float hv = h[k];
    pc += hv * Wc[k];
    p0 += hv * Wa[k];
    p1 += hv * Wa[512 + k];
    p2 += hv * Wa[1024 + k];
    p3 += hv * Wa[1536 + k];
  }
#pragma unroll
  for (int m = 1; m < 64; m <<= 1) {
    pc += __shfl_xor(pc, m);
    p0 += __shfl_xor(p0, m);
    p1 += __shfl_xor(p1, m);
    p2 += __shfl_xor(p2, m);
    p3 += __shfl_xor(p3, m);
  }
  float v = pc + bc[0];
  float k0 = p0 + ba[0], k1 = p1 + ba[1], k2 = p2 + ba[2], k3 = p3 + ba[3];
  float mx = fmaxf(k0, fmaxf(k1, k2));
  float e0 = __expf(k0 - mx), e1 = __expf(k1 - mx), e2 = __expf(k2 - mx);
  float es = e0 + e1 + e2;
  float l0 = e0 / es, l1 = e1 / es, l2 = e2 / es;
  float no = sigm(k3);
  float total = (1.0f - no) * (l0 + l1 + l2) + no;
  float sc = (1.0f - no) / total;
  int q = qpre[row], qp = qpost[row];
  int a = actions[row];
  if (lane == 0) {
    out[(size_t)row * S_] = (float)a;
    out[(size_t)row * S_ + 1] = v;
  }
  float* pr = out + (size_t)row * S_ + 2 + H_;
  for (int c = lane; c < L_ + 1; c += 64) {
    float val;
    if (c == L_) val = no / total;
    else {
      val = 0.f;
      if (q == 0)            { if (c == 0) val = l1 + l2; else if (c == 1) val = l0; }
      else if (q == L_ - 1)  { if (c == L_ - 2) val = l2; else if (c == L_ - 1) val = l0 + l1; }
      else                   { if (c == q - 1) val = l2; else if (c == q) val = l1; else if (c == q + 1) val = l0; }
      val *= sc;
    }
    pr[c] = val;
  }
  float* pp = pr + (L_ + 1);
  for (int c = lane; c < L_; c += 64) pp[c] = (c == qp) ? 1.0f : 0.0f;
}

__global__ void copy_last(float* __restrict__ out) {
  int i = blockIdx.x * 256 + threadIdx.x;
  if (i < N_ * S_) out[(size_t)TN_ * S_ + i] = out[(size_t)(T_ - 1) * N_ * S_ + i];
}

// ---------------- launch ----------------
extern "C" void kernel_launch(void* const* d_in, const int* in_sizes, int n_in,
                              void* d_out, int out_size, void* d_ws, size_t ws_size,
                              hipStream_t stream) {
  const float* cond = (const float*)d_in[0];
  const float* hxs  = (const float*)d_in[1];
  const float* emb  = (const float*)d_in[2];
  const float* W0   = (const float*)d_in[3];
  const float* b0   = (const float*)d_in[4];
  const float* W1   = (const float*)d_in[5];
  const float* b1   = (const float*)d_in[6];
  const float* W2   = (const float*)d_in[7];
  const float* b2   = (const float*)d_in[8];
  const float* Wih  = (const float*)d_in[9];
  const float* bih  = (const float*)d_in[10];
  const float* Whh  = (const float*)d_in[11];
  const float* bhh  = (const float*)d_in[12];
  const float* Wc   = (const float*)d_in[13];
  const float* bc   = (const float*)d_in[14];
  const float* Wa   = (const float*)d_in[15];
  const float* ba   = (const float*)d_in[16];
  const int* lines   = (const int*)d_in[17];
  const int* actions = (const int*)d_in[18];
  float* out = (float*)d_out;

  char* ws = (char*)d_ws;
  size_t off = 0;
  auto alloc = [&](size_t bytes) {
    char* p = ws + off;
    off += (bytes + 255) & ~(size_t)255;
    return p;
  };
  u16* P = (u16*)alloc((size_t)TN_ * 576 * 2);   // Abuf, then X2
  u16* Q = (u16*)alloc((size_t)TN_ * 512 * 2);   // X1, then X3
  u16* GIb = (u16*)alloc((size_t)TN_ * 1536 * 2); // gi (201MB)
  u16* Abuf = P;
  u16* X1 = Q;
  u16* X2 = P;
  u16* X3 = Q;
  u16* W0b = (u16*)alloc((size_t)512 * 576 * 2);
  u16* W1b = (u16*)alloc((size_t)512 * 512 * 2);
  u16* W2b = (u16*)alloc((size_t)512 * 512 * 2);
  u16* WIHb = (u16*)alloc((size_t)1536 * 512 * 2);
  u16* WHHb = (u16*)alloc((size_t)1536 * 512 * 2);
  int* qpre  = (int*)alloc((size_t)TN_ * 4);
  int* qpost = (int*)alloc((size_t)TN_ * 4);
  u16* hb0 = (u16*)alloc((size_t)N_ * 512 * 2);
  u16* hb1 = (u16*)alloc((size_t)N_ * 512 * 2);
  int* bar = (int*)alloc((size_t)16 * T_ * 4);

  hipMemsetAsync(bar, 0, (size_t)16 * T_ * 4, stream);

  cast_f32_bf16<<<(512 * 576 + 255) / 256, 256, 0, stream>>>(W0, W0b, 512 * 576);
  cast_f32_bf16<<<(512 * 512 + 255) / 256, 256, 0, stream>>>(W1, W1b, 512 * 512);
  cast_f32_bf16<<<(512 * 512 + 255) / 256, 256, 0, stream>>>(W2, W2b, 512 * 512);
  cast_f32_bf16<<<(1536 * 512 + 255) / 256, 256, 0, stream>>>(Wih, WIHb, 1536 * 512);
  cast_f32_bf16<<<(1536 * 512 + 255) / 256, 256, 0, stream>>>(Whh, WHHb, 1536 * 512);
  qscan<<<4, 256, 0, stream>>>(hxs, actions, qpre, qpost);
  hbf_init<<<(N_ * 512 + 255) / 256, 256, 0, stream>>>(hxs, hb0);
  build_abuf<<<TN_ / 4, 256, 0, stream>>>(cond, emb, lines, qpre, Abuf);

  gemm_nt<<<dim3(4, 512), 256, 0, stream>>>(Abuf, 576, W0b, 576, b0, X1, 512, 576, 1);
  gemm_nt<<<dim3(4, 512), 256, 0, stream>>>(X1, 512, W1b, 512, b1, X2, 512, 512, 1);
  gemm_nt<<<dim3(4, 512), 256, 0, stream>>>(X2, 512, W2b, 512, b2, X3, 512, 512, 1);
  gemm_nt<<<dim3(12, 512), 256, 0, stream>>>(X3, 512, WIHb, 512, bih, GIb, 1536, 512, 0);

  gru_persistent<<<256, 256, 0, stream>>>(GIb, WHHb, hb0, hb1, hxs, bhh, out, bar);

  heads_kernel<<<TN_ / 4, 256, 0, stream>>>(Wc, bc, Wa, ba, actions, qpre, qpost, out);
  copy_last<<<(N_ * S_ + 255) / 256, 256, 0, stream>>>(out);
}